// Round 1
// baseline (177.812 us; speedup 1.0000x reference)
//
#include <hip/hip_runtime.h>

// GAE scan: T=2048 rollout steps, N=4096 envs, fp32.
// adv[t] = delta[t] + c[t]*adv[t+1],  c[t] = GAMMA*LAMBDA*(1-dones[t+1])
// delta[t] = rewards[t] + GAMMA*values[t+1]*(1-dones[t+1]) - values[t]
// Parallelized as a chunked (blocked) linear-recurrence scan:
//   phase1: per-(chunk,env) compose affine transform adv[t0] = P + A*adv[t0+L]
//   phase2: per-env sequential scan over the C chunk summaries -> incoming adv per chunk
//   phase3: per-(chunk,env) replay chunk with known incoming adv, write adv & returns.

#define T_LEN    2048
#define N_ENV    4096
#define N_CHUNKS 64
#define CHUNK_L  (T_LEN / N_CHUNKS)   // 32

__constant__ float kGamma_unused; // (avoid accidental symbol issues; constants below are constexpr)

static constexpr float GAMMA = 0.99f;
static constexpr float GL    = 0.99f * 0.95f;   // gamma * gae_lambda

__global__ __launch_bounds__(256) void gae_phase1(
    const float* __restrict__ rewards,
    const float* __restrict__ values,
    const float* __restrict__ dones,
    float* __restrict__ Aout,   // [N_CHUNKS * N_ENV]
    float* __restrict__ Pout)   // [N_CHUNKS * N_ENV]
{
    const int idx = blockIdx.x * blockDim.x + threadIdx.x;  // c*N_ENV + n (n fastest -> coalesced)
    if (idx >= N_CHUNKS * N_ENV) return;
    const int n = idx & (N_ENV - 1);
    const int c = idx >> 12;            // idx / 4096
    const int t_hi = c * CHUNK_L + (CHUNK_L - 1);

    float v_next, d_next;
    if (c == N_CHUNKS - 1) { v_next = 0.0f; d_next = 1.0f; }
    else {
        v_next = values[(t_hi + 1) * N_ENV + n];
        d_next = dones [(t_hi + 1) * N_ENV + n];
    }

    const float* rp = rewards + (size_t)t_hi * N_ENV + n;
    const float* vp = values  + (size_t)t_hi * N_ENV + n;
    const float* dp = dones   + (size_t)t_hi * N_ENV + n;

    float A = 1.0f, P = 0.0f;
    #pragma unroll 4
    for (int i = 0; i < CHUNK_L; ++i) {
        const float r = *rp, v = *vp, d = *dp;
        const float nt    = 1.0f - d_next;
        const float delta = fmaf(GAMMA * v_next, nt, r) - v;
        const float cc    = GL * nt;
        P = fmaf(cc, P, delta);
        A = cc * A;
        v_next = v; d_next = d;
        rp -= N_ENV; vp -= N_ENV; dp -= N_ENV;
    }
    Aout[idx] = A;
    Pout[idx] = P;
}

__global__ __launch_bounds__(256) void gae_phase2(
    const float* __restrict__ Ain,
    const float* __restrict__ Pin,
    float* __restrict__ inc)    // [N_CHUNKS * N_ENV]: adv at step (t0(c)+L) for chunk c
{
    const int n = blockIdx.x * blockDim.x + threadIdx.x;
    if (n >= N_ENV) return;
    float b = 0.0f;  // adv beyond last step = 0
    for (int c = N_CHUNKS - 1; c >= 0; --c) {
        inc[c * N_ENV + n] = b;
        b = fmaf(Ain[c * N_ENV + n], b, Pin[c * N_ENV + n]);
    }
}

__global__ __launch_bounds__(256) void gae_phase3(
    const float* __restrict__ rewards,
    const float* __restrict__ values,
    const float* __restrict__ dones,
    const float* __restrict__ inc,
    float* __restrict__ out)    // [2 * T_LEN * N_ENV]: advantages then returns
{
    const int idx = blockIdx.x * blockDim.x + threadIdx.x;
    if (idx >= N_CHUNKS * N_ENV) return;
    const int n = idx & (N_ENV - 1);
    const int c = idx >> 12;
    const int t_hi = c * CHUNK_L + (CHUNK_L - 1);

    float v_next, d_next;
    if (c == N_CHUNKS - 1) { v_next = 0.0f; d_next = 1.0f; }
    else {
        v_next = values[(t_hi + 1) * N_ENV + n];
        d_next = dones [(t_hi + 1) * N_ENV + n];
    }

    const float* rp = rewards + (size_t)t_hi * N_ENV + n;
    const float* vp = values  + (size_t)t_hi * N_ENV + n;
    const float* dp = dones   + (size_t)t_hi * N_ENV + n;
    float*       ap = out     + (size_t)t_hi * N_ENV + n;                       // advantages
    float*       gp = out     + (size_t)(T_LEN + t_hi) * N_ENV + n;             // returns

    float adv = inc[idx];   // incoming adv from the chunk above
    #pragma unroll 4
    for (int i = 0; i < CHUNK_L; ++i) {
        const float r = *rp, v = *vp, d = *dp;
        const float nt    = 1.0f - d_next;
        const float delta = fmaf(GAMMA * v_next, nt, r) - v;
        const float cc    = GL * nt;
        adv = fmaf(cc, adv, delta);
        *ap = adv;
        *gp = adv + v;
        v_next = v; d_next = d;
        rp -= N_ENV; vp -= N_ENV; dp -= N_ENV;
        ap -= N_ENV; gp -= N_ENV;
    }
}

extern "C" void kernel_launch(void* const* d_in, const int* in_sizes, int n_in,
                              void* d_out, int out_size, void* d_ws, size_t ws_size,
                              hipStream_t stream) {
    const float* rewards = (const float*)d_in[0];
    const float* values  = (const float*)d_in[1];
    const float* dones   = (const float*)d_in[2];
    float* out = (float*)d_out;

    // Workspace layout (fp32): A | P | inc, each N_CHUNKS*N_ENV elements (1 MB each).
    float* A   = (float*)d_ws;
    float* P   = A + (size_t)N_CHUNKS * N_ENV;
    float* inc = P + (size_t)N_CHUNKS * N_ENV;

    const int total = N_CHUNKS * N_ENV;           // 262144
    const int blk = 256;

    gae_phase1<<<total / blk, blk, 0, stream>>>(rewards, values, dones, A, P);
    gae_phase2<<<N_ENV / blk, blk, 0, stream>>>(A, P, inc);
    gae_phase3<<<total / blk, blk, 0, stream>>>(rewards, values, dones, inc, out);
}

// Round 2
// 169.888 us; speedup vs baseline: 1.0466x; 1.0466x over previous
//
#include <hip/hip_runtime.h>

// GAE scan: T=2048, N=4096, fp32. Chunked linear-recurrence scan, 3 phases:
//   phase1: per-(chunk, env4) compose affine adv[t0] = P + A*adv[t0+L]  (float4 over envs)
//   phase2: one WAVE per env — affine suffix scan over the 64 chunk summaries via shfl
//   phase3: replay each chunk with known incoming adv, write adv & returns (float4)

#define T_LEN    2048
#define N_ENV    4096
#define NV4      (N_ENV / 4)          // 1024 float4 columns
#define N_CHUNKS 64                   // == wave size, enables the shfl scan in phase2
#define CHUNK_L  (T_LEN / N_CHUNKS)   // 32

static constexpr float GAMMA = 0.99f;
static constexpr float GL    = 0.99f * 0.95f;   // gamma * gae_lambda

__global__ __launch_bounds__(256) void gae_phase1(
    const float4* __restrict__ rewards,   // [T_LEN][NV4]
    const float4* __restrict__ values,
    const float4* __restrict__ dones,
    float4* __restrict__ Aout,            // [N_CHUNKS][NV4]
    float4* __restrict__ Pout)
{
    const int idx = blockIdx.x * blockDim.x + threadIdx.x;   // c*NV4 + n4
    if (idx >= N_CHUNKS * NV4) return;
    const int n4 = idx & (NV4 - 1);
    const int c  = idx >> 10;
    const int t_hi = c * CHUNK_L + (CHUNK_L - 1);

    float4 v_next, d_next;
    if (c == N_CHUNKS - 1) {
        v_next = make_float4(0.f, 0.f, 0.f, 0.f);
        d_next = make_float4(1.f, 1.f, 1.f, 1.f);
    } else {
        v_next = values[(t_hi + 1) * NV4 + n4];
        d_next = dones [(t_hi + 1) * NV4 + n4];
    }

    float4 A = make_float4(1.f, 1.f, 1.f, 1.f);
    float4 P = make_float4(0.f, 0.f, 0.f, 0.f);

    #pragma unroll 8
    for (int i = 0; i < CHUNK_L; ++i) {
        const int t = t_hi - i;
        const float4 r = rewards[t * NV4 + n4];
        const float4 v = values [t * NV4 + n4];
        const float4 d = dones  [t * NV4 + n4];
        #define STEP(X) { \
            const float nt    = 1.0f - d_next.X; \
            const float delta = fmaf(GAMMA * v_next.X, nt, r.X) - v.X; \
            const float cc    = GL * nt; \
            P.X = fmaf(cc, P.X, delta); \
            A.X = cc * A.X; \
            v_next.X = v.X; d_next.X = d.X; }
        STEP(x) STEP(y) STEP(z) STEP(w)
        #undef STEP
    }
    Aout[idx] = A;
    Pout[idx] = P;
}

// One wave per env. Lane c holds chunk c's affine f_c(x) = P + A*x.
// Inclusive suffix composition F_c = f_c ∘ f_{c+1} ∘ ... ∘ f_{63}; then
// incoming adv for chunk c is b[c] = F_{c+1}(0) = P of lane c+1 (b[63] = 0).
__global__ __launch_bounds__(256) void gae_phase2(
    const float* __restrict__ Ain,    // [N_CHUNKS][N_ENV]
    const float* __restrict__ Pin,
    float* __restrict__ inc)          // [N_CHUNKS][N_ENV]
{
    const int tid  = blockIdx.x * blockDim.x + threadIdx.x;
    const int n    = tid >> 6;               // wave id = env
    const int lane = tid & 63;
    if (n >= N_ENV) return;

    float Ax = Ain[lane * N_ENV + n];
    float Px = Pin[lane * N_ENV + n];

    #pragma unroll
    for (int off = 1; off < 64; off <<= 1) {
        const float Ap = __shfl_down(Ax, off, 64);
        const float Pp = __shfl_down(Px, off, 64);
        const bool valid = (lane + off) < 64;
        const float Pn = valid ? fmaf(Ax, Pp, Px) : Px;  // self ∘ partner
        const float An = valid ? Ax * Ap       : Ax;
        Px = Pn; Ax = An;
    }
    const float bP = __shfl_down(Px, 1, 64);
    inc[lane * N_ENV + n] = (lane == 63) ? 0.0f : bP;
}

__global__ __launch_bounds__(256) void gae_phase3(
    const float4* __restrict__ rewards,
    const float4* __restrict__ values,
    const float4* __restrict__ dones,
    const float4* __restrict__ inc,   // [N_CHUNKS][NV4]
    float4* __restrict__ out)         // [2*T_LEN][NV4]: advantages then returns
{
    const int idx = blockIdx.x * blockDim.x + threadIdx.x;
    if (idx >= N_CHUNKS * NV4) return;
    const int n4 = idx & (NV4 - 1);
    const int c  = idx >> 10;
    const int t_hi = c * CHUNK_L + (CHUNK_L - 1);

    float4 v_next, d_next;
    if (c == N_CHUNKS - 1) {
        v_next = make_float4(0.f, 0.f, 0.f, 0.f);
        d_next = make_float4(1.f, 1.f, 1.f, 1.f);
    } else {
        v_next = values[(t_hi + 1) * NV4 + n4];
        d_next = dones [(t_hi + 1) * NV4 + n4];
    }

    float4 adv = inc[idx];

    #pragma unroll 8
    for (int i = 0; i < CHUNK_L; ++i) {
        const int t = t_hi - i;
        const float4 r = rewards[t * NV4 + n4];
        const float4 v = values [t * NV4 + n4];
        const float4 d = dones  [t * NV4 + n4];
        float4 ret;
        #define STEP(X) { \
            const float nt    = 1.0f - d_next.X; \
            const float delta = fmaf(GAMMA * v_next.X, nt, r.X) - v.X; \
            const float cc    = GL * nt; \
            adv.X = fmaf(cc, adv.X, delta); \
            ret.X = adv.X + v.X; \
            v_next.X = v.X; d_next.X = d.X; }
        STEP(x) STEP(y) STEP(z) STEP(w)
        #undef STEP
        out[t * NV4 + n4]           = adv;   // advantages
        out[(T_LEN + t) * NV4 + n4] = ret;   // returns
    }
}

extern "C" void kernel_launch(void* const* d_in, const int* in_sizes, int n_in,
                              void* d_out, int out_size, void* d_ws, size_t ws_size,
                              hipStream_t stream) {
    const float4* rewards = (const float4*)d_in[0];
    const float4* values  = (const float4*)d_in[1];
    const float4* dones   = (const float4*)d_in[2];
    float4* out = (float4*)d_out;

    // Workspace: A | P | inc, each N_CHUNKS*N_ENV fp32 (1 MB each); all fully
    // written before read every launch (0xAA poison safe).
    float* A   = (float*)d_ws;
    float* P   = A + (size_t)N_CHUNKS * N_ENV;
    float* inc = P + (size_t)N_CHUNKS * N_ENV;

    const int blk = 256;
    gae_phase1<<<(N_CHUNKS * NV4) / blk, blk, 0, stream>>>(
        rewards, values, dones, (float4*)A, (float4*)P);
    gae_phase2<<<(N_ENV * 64) / blk, blk, 0, stream>>>(A, P, inc);
    gae_phase3<<<(N_CHUNKS * NV4) / blk, blk, 0, stream>>>(
        rewards, values, dones, (const float4*)inc, out);
}